// Round 6
// baseline (126.773 us; speedup 1.0000x reference)
//
#include <hip/hip_runtime.h>

#define T_LEN 1024
#define B_LEN 64

typedef float v2f __attribute__((ext_vector_type(2)));

// One DPP-add level: x += dpp_move(x, CTRL), out-of-bounds lanes read 0.
template <int CTRL>
__device__ __forceinline__ float dpp_add(float x)
{
    int y = __builtin_amdgcn_update_dpp(0, __builtin_bit_cast(int, x), CTRL, 0xf, 0xf, true);
    return x + __builtin_bit_cast(float, y);
}
__device__ __forceinline__ v2f fma2(v2f a, v2f b, v2f c) { return __builtin_elementwise_fma(a, b, c); }
__device__ __forceinline__ float rl63(float x)
{
    return __builtin_bit_cast(float, __builtin_amdgcn_readlane(__builtin_bit_cast(int, x), 63));
}

// Lag-2 scaled HMM forward. a_t = b_t + KE*Z_{t-1}*E_t with b_t = E_t o 0.9 a_{t-1}:
//   vector:  b_t = E_t o (0.9 b_{t-1} + 0.9*KE*Z_{t-2} * E_{t-1})   (Z lagged 2!)
//   scalar:  Z_t = U_t + KE*V_t*Z_{t-1},  U_t = sum(b_t), V_t = sum(E_t)
// Each body DPP-reduces the PREVIOUS step's U/V trees while computing this
// step's b-update, so the ~120cy cross-lane latency amortizes over a full step.
// Renorm every 8 steps applied as a one-body-late fixup (r = rcp(Z), scale b9,U).
__global__ __launch_bounds__(64) void hmm_fwd_kernel(const float* __restrict__ obvs,
                                                     const float* __restrict__ mu,
                                                     const float* __restrict__ ln_pi,
                                                     float* __restrict__ out)
{
    const int b = blockIdx.x;
    const int lane = threadIdx.x;

    __shared__ __align__(16) float s_obs[T_LEN + 8];
    const float* orow = obvs + (size_t)b * T_LEN;
#pragma unroll
    for (int k = 0; k < T_LEN / 64; ++k) s_obs[lane + 64 * k] = orow[lane + 64 * k];
    if (lane < 8) s_obs[T_LEN + lane] = 0.0f;
    __syncthreads();

    const float C1    = -0.7213475204444817f;   // -0.5*log2(e)
    const float C2    = -1.3257480647361593f;   // -0.5*log2(2*pi)
    const float LOG2E =  1.4426950408889634f;
    const float KE    =  0.1f / 512.0f;
    const float C09KE =  0.9f * (0.1f / 512.0f);
    const float LN2   =  0.6931471805599453f;

    v2f mp2[4], mq2[4], lp2[4];
    {
        const float4 mua = reinterpret_cast<const float4*>(mu)[2 * lane];
        const float4 mub = reinterpret_cast<const float4*>(mu)[2 * lane + 1];
        const float4 pia = reinterpret_cast<const float4*>(ln_pi)[2 * lane];
        const float4 pib = reinterpret_cast<const float4*>(ln_pi)[2 * lane + 1];
        const float m[8]  = {mua.x, mua.y, mua.z, mua.w, mub.x, mub.y, mub.z, mub.w};
        const float lp[8] = {pia.x, pia.y, pia.z, pia.w, pib.x, pib.y, pib.z, pib.w};
#pragma unroll
        for (int i = 0; i < 4; ++i) {
            mp2[i] = (v2f){-2.0f * C1 * m[2 * i], -2.0f * C1 * m[2 * i + 1]};
            mq2[i] = (v2f){fmaf(C1 * m[2 * i], m[2 * i], C2),
                           fmaf(C1 * m[2 * i + 1], m[2 * i + 1], C2)};
            lp2[i] = (v2f){lp[2 * i] * LOG2E, lp[2 * i + 1] * LOG2E};
        }
    }

    // pipeline registers (entering body tau):
    //  b9   = 0.9*b_{tau-1}, eprev = E_{tau-1}, ecur = E_tau
    //  lU   = tree(b_{tau-1}), lE = tree(E_tau)
    //  kvE  = KE*V_{tau-1},  Zreg = Z_{tau-2}
    v2f b9[4], eprev[4], ecur[4];
    float lU, lE, kvE, Zreg;
    float acc2 = 0.0f;
    v2f osq2 = (v2f){0.0f, 0.0f};
    float oc[8], on[8];
    const v2f c9v = (v2f){0.9f, 0.9f};

    auto body = [&](float onext, bool fixup) {
        float r = 0.0f;
        if (fixup) {                                     // renorm of Z_{tau-2}=Z_t*
            acc2 += __builtin_amdgcn_logf(Zreg);         // log2
            r = __builtin_amdgcn_rcpf(Zreg);
        }
        // launch cross-lane chains for the PREVIOUS step's trees
        float u = dpp_add<0x111>(lU);
        float v = dpp_add<0x111>(lE);
        v2f w2v;
        if (fixup) {
            w2v = (v2f){C09KE, C09KE};                   // Z_{t*} scaled to 1
            const v2f rv = (v2f){r, r};
#pragma unroll
            for (int i = 0; i < 4; ++i) b9[i] *= rv;     // rescale vector state
        } else {
            const float w2 = C09KE * Zreg;
            w2v = (v2f){w2, w2};
        }
        u = dpp_add<0x112>(u);
        v = dpp_add<0x112>(v);
        // b_tau = E_tau o (0.9 b_{tau-1} + 0.9KE*Z_{tau-2} * E_{tau-1})
        v2f bb[4];
#pragma unroll
        for (int i = 0; i < 4; ++i) bb[i] = ecur[i] * fma2(eprev[i], w2v, b9[i]);
        u = dpp_add<0x114>(u);
        v = dpp_add<0x114>(v);
        v2f s0 = bb[0] + bb[1];
        v2f s1 = bb[2] + bb[3];
        v2f ss = s0 + s1;
        const float lb = ss[0] + ss[1];                  // tree(b_tau)
        // emissions for step tau+1
        const v2f ov = (v2f){onext, onext};
        v2f en[4];
#pragma unroll
        for (int i = 0; i < 4; ++i) {
            v2f q = fma2(mp2[i], ov, mq2[i]);
            en[i] = (v2f){__builtin_amdgcn_exp2f(q[0]), __builtin_amdgcn_exp2f(q[1])};
        }
        u = dpp_add<0x118>(u);
        v = dpp_add<0x118>(v);
        v2f t0 = en[0] + en[1];
        v2f t1 = en[2] + en[3];
        v2f tt = t0 + t1;
        const float le = tt[0] + tt[1];                  // tree(E_{tau+1})
        u = dpp_add<0x142>(u);
        v = dpp_add<0x142>(v);
#pragma unroll
        for (int i = 0; i < 4; ++i) b9[i] = c9v * bb[i]; // next body's 0.9*b
        u = dpp_add<0x143>(u);
        v = dpp_add<0x143>(v);
        const float U = rl63(u);                         // U_{tau-1}
        const float V = rl63(v);                         // V_tau
        float Zn;
        if (fixup) Zn = fmaf(U, r, kvE);                 // U*r + kvE*1
        else       Zn = fmaf(kvE, Zreg, U);              // Z_{tau-1}
        kvE = KE * V;
        Zreg = Zn;
        lU = lb;
        lE = le;
#pragma unroll
        for (int i = 0; i < 4; ++i) { eprev[i] = ecur[i]; ecur[i] = en[i]; }
    };

#pragma unroll
    for (int j = 0; j < 8; ++j) oc[j] = s_obs[j];
#pragma unroll
    for (int j = 0; j < 8; ++j) on[j] = s_obs[8 + j];

    {   // prologue: t=0,1 and pipeline priming for body tau=2
        const v2f o0 = (v2f){oc[0], oc[0]};
        v2f a0[4];
#pragma unroll
        for (int i = 0; i < 4; ++i) {
            v2f q = fma2(mp2[i], o0, mq2[i]) + lp2[i];
            a0[i] = (v2f){__builtin_amdgcn_exp2f(q[0]), __builtin_amdgcn_exp2f(q[1])};
        }
        const v2f o1 = (v2f){oc[1], oc[1]};
        v2f e1[4];
#pragma unroll
        for (int i = 0; i < 4; ++i) {
            v2f q = fma2(mp2[i], o1, mq2[i]);
            e1[i] = (v2f){__builtin_amdgcn_exp2f(q[0]), __builtin_amdgcn_exp2f(q[1])};
        }
        v2f b1[4];
#pragma unroll
        for (int i = 0; i < 4; ++i) b1[i] = e1[i] * (c9v * a0[i]);   // b_1 = E_1 o 0.9 a_0
        // interleaved reduces: Z_0 = sum(a0), V_1 = sum(e1)
        v2f za2 = (a0[0] + a0[1]) + (a0[2] + a0[3]);
        v2f ve2 = (e1[0] + e1[1]) + (e1[2] + e1[3]);
        float za = za2[0] + za2[1];
        float ve = ve2[0] + ve2[1];
        za = dpp_add<0x111>(za); ve = dpp_add<0x111>(ve);
        za = dpp_add<0x112>(za); ve = dpp_add<0x112>(ve);
        za = dpp_add<0x114>(za); ve = dpp_add<0x114>(ve);
        za = dpp_add<0x118>(za); ve = dpp_add<0x118>(ve);
        za = dpp_add<0x142>(za); ve = dpp_add<0x142>(ve);
        za = dpp_add<0x143>(za); ve = dpp_add<0x143>(ve);
        Zreg = rl63(za);                 // Z_0
        kvE  = KE * rl63(ve);            // KE*V_1
        // E_2 and trees
        const v2f o2 = (v2f){oc[2], oc[2]};
        v2f e2[4];
#pragma unroll
        for (int i = 0; i < 4; ++i) {
            v2f q = fma2(mp2[i], o2, mq2[i]);
            e2[i] = (v2f){__builtin_amdgcn_exp2f(q[0]), __builtin_amdgcn_exp2f(q[1])};
        }
        v2f lb2 = (b1[0] + b1[1]) + (b1[2] + b1[3]);
        v2f le2 = (e2[0] + e2[1]) + (e2[2] + e2[3]);
        lU = lb2[0] + lb2[1];            // tree(b_1)
        lE = le2[0] + le2[1];            // tree(E_2)
#pragma unroll
        for (int i = 0; i < 4; ++i) {
            b9[i] = c9v * b1[i];
            eprev[i] = e1[i];
            ecur[i] = e2[i];
        }
    }
#pragma unroll
    for (int j = 0; j < 8; j += 2)       // osq over t=0..7
        osq2 = fma2((v2f){oc[j], oc[j + 1]}, (v2f){oc[j], oc[j + 1]}, osq2);

    // prologue bodies tau = 2..7 (no renorm fixups in this range)
    body(oc[3], false);
    body(oc[4], false);
    body(oc[5], false);
    body(oc[6], false);
    body(oc[7], false);
    body(on[0], false);
#pragma unroll
    for (int j = 0; j < 8; ++j) oc[j] = on[j];

    // groups g=1..127: bodies tau = 8g..8g+7; fixup at tau==8g+1 (renorm of t*=8g-1)
#pragma unroll 1
    for (int g = 1; g < 128; ++g) {
        const float4 n0 = *reinterpret_cast<const float4*>(&s_obs[8 * g + 8]);
        const float4 n1 = *reinterpret_cast<const float4*>(&s_obs[8 * g + 12]);
#pragma unroll
        for (int j = 0; j < 8; j += 2)   // osq over t=8g..8g+7
            osq2 = fma2((v2f){oc[j], oc[j + 1]}, (v2f){oc[j], oc[j + 1]}, osq2);
        body(oc[1], false);
        body(oc[2], true);               // fixup: renorm of Z_{8g-1}
        body(oc[3], false);
        body(oc[4], false);
        body(oc[5], false);
        body(oc[6], false);
        body(oc[7], false);
        body(n0.x, false);
        oc[0] = n0.x; oc[1] = n0.y; oc[2] = n0.z; oc[3] = n0.w;
        oc[4] = n1.x; oc[5] = n1.y; oc[6] = n1.z; oc[7] = n1.w;
    }

    // epilogue: finish Z_1023 = U_1023 + KE*V_1023*Z_1022
    {
        float u = dpp_add<0x111>(lU);
        u = dpp_add<0x112>(u);
        u = dpp_add<0x114>(u);
        u = dpp_add<0x118>(u);
        u = dpp_add<0x142>(u);
        u = dpp_add<0x143>(u);
        const float U = rl63(u);
        const float Zf = fmaf(kvE, Zreg, U);
        acc2 += __builtin_amdgcn_logf(Zf);
    }

    if (lane == 0)
        atomicAdd(out, LN2 * (acc2 + C1 * (osq2[0] + osq2[1])));
}

extern "C" void kernel_launch(void* const* d_in, const int* in_sizes, int n_in,
                              void* d_out, int out_size, void* d_ws, size_t ws_size,
                              hipStream_t stream)
{
    const float* obvs  = (const float*)d_in[0];
    const float* mu    = (const float*)d_in[1];
    const float* ln_pi = (const float*)d_in[2];
    float* out = (float*)d_out;

    (void)hipMemsetAsync(out, 0, sizeof(float), stream);
    hmm_fwd_kernel<<<B_LEN, 64, 0, stream>>>(obvs, mu, ln_pi, out);
}

// Round 7
// 40.262 us; speedup vs baseline: 3.1487x; 3.1487x over previous
//
#include <hip/hip_runtime.h>

#define T_LEN 1024
#define B_LEN 64
#define NCHUNK 16
#define CLEN 64          // work steps per chunk
#define BURN_MAX 160     // burn-in steps (0.9^160 ~ 5e-8 forgetting)

typedef float v2f __attribute__((ext_vector_type(2)));

// One DPP-add level: x += dpp_move(x, CTRL), out-of-bounds lanes read 0.
template <int CTRL>
__device__ __forceinline__ float dpp_add(float x)
{
    int y = __builtin_amdgcn_update_dpp(0, __builtin_bit_cast(int, x), CTRL, 0xf, 0xf, true);
    return x + __builtin_bit_cast(float, y);
}
__device__ __forceinline__ v2f fma2(v2f a, v2f b, v2f c) { return __builtin_elementwise_fma(a, b, c); }

// Time-chunked scaled HMM forward. Block = (row b, chunk c). Chunk work region
// is t in [64c, 64c+64); chunks with t0>0 burn in from a uniform start for up
// to 160 steps (leak eps=0.1 mixes at 0.9^k), then the boundary reset discards
// burn-in accumulators. Chunks starting at t=0 (c=0,1,2) are exact (init pi).
// Per-wave step body is the R5 structure: lane owns 8 states as 4 packed-f32
// pairs, DPP wave-reduce interleaved with next-step emission prep, renorm every
// 8 steps folded into next step's coefficients, state-uniform exp2(C1*o^2)
// factor dropped and restored at the end via C1*sum(o^2) over the work region.
__global__ __launch_bounds__(64) void hmm_fwd_kernel(const float* __restrict__ obvs,
                                                     const float* __restrict__ mu,
                                                     const float* __restrict__ ln_pi,
                                                     float* __restrict__ out)
{
    const int bid  = blockIdx.x;
    const int b    = bid >> 4;          // batch row
    const int c    = bid & 15;          // time chunk
    const int lane = threadIdx.x;

    const int burn    = (64 * c < BURN_MAX) ? 64 * c : BURN_MAX;
    const int t0      = 64 * c - burn;  // first step this block simulates
    const int ng      = (burn + CLEN) >> 3;   // groups of 8 steps (incl. init group)
    const int g_reset = burn >> 3;            // discard accumulators entering this group
    const int wlen    = 8 * ng + 8;           // obs window incl. prefetch pad

    __shared__ __align__(16) float s_obs[BURN_MAX + CLEN + 16];
    const float* orow = obvs + (size_t)b * T_LEN;
#pragma unroll
    for (int k = 0; k < 4; ++k) {
        const int idx = lane + 64 * k;
        float v = 0.0f;
        if (idx < wlen && (t0 + idx) < T_LEN) v = orow[t0 + idx];
        if (idx < (int)(sizeof(s_obs) / sizeof(float))) s_obs[idx] = v;
    }
    __syncthreads();

    const float C1    = -0.7213475204444817f;   // -0.5 * log2(e)
    const float C2    = -1.3257480647361593f;   // -0.5 * log2(2*pi)
    const float LOG2E =  1.4426950408889634f;
    const float KE    =  0.1f / 512.0f;         // eps / S
    const float LN2   =  0.6931471805599453f;

    // per-state constants: reduced emission exponent q~ = mp*o + mq
    v2f mp2[4], mq2[4], lp2[4];
    {
        const float4 mua = reinterpret_cast<const float4*>(mu)[2 * lane];
        const float4 mub = reinterpret_cast<const float4*>(mu)[2 * lane + 1];
        const float4 pia = reinterpret_cast<const float4*>(ln_pi)[2 * lane];
        const float4 pib = reinterpret_cast<const float4*>(ln_pi)[2 * lane + 1];
        const float m[8]  = {mua.x, mua.y, mua.z, mua.w, mub.x, mub.y, mub.z, mub.w};
        const float lp[8] = {pia.x, pia.y, pia.z, pia.w, pib.x, pib.y, pib.z, pib.w};
#pragma unroll
        for (int i = 0; i < 4; ++i) {
            mp2[i] = (v2f){-2.0f * C1 * m[2 * i], -2.0f * C1 * m[2 * i + 1]};
            mq2[i] = (v2f){fmaf(C1 * m[2 * i], m[2 * i], C2),
                           fmaf(C1 * m[2 * i + 1], m[2 * i + 1], C2)};
            // exact init (log pi) when the chunk starts at t=0; uniform otherwise
            lp2[i] = (t0 == 0) ? (v2f){lp[2 * i] * LOG2E, lp[2 * i + 1] * LOG2E}
                               : (v2f){0.0f, 0.0f};
        }
    }

    v2f a2[4], e2[4];          // alpha and current-step emissions
    float Z;
    v2f c9v, kzv;
    float acc2 = 0.0f;         // accumulated log2 of normalization scales
    v2f osq2 = (v2f){0.0f, 0.0f};

    auto stepf = [&](float on, bool renorm) {
        // advance alpha with current emissions (chain: Z -> kzv -> fma -> mul)
#pragma unroll
        for (int i = 0; i < 4; ++i) {
            v2f w = fma2(a2[i], c9v, kzv);
            a2[i] = e2[i] * w;
        }
        v2f s0 = a2[0] + a2[1];
        v2f s1 = a2[2] + a2[3];
        v2f ss = s0 + s1;
        float l = ss[0] + ss[1];
        // next-step emission prep, interleaved with the DPP reduce
        const v2f o2 = (v2f){on, on};
        v2f q0 = fma2(mp2[0], o2, mq2[0]);
        v2f q1 = fma2(mp2[1], o2, mq2[1]);
        l = dpp_add<0x111>(l);                       // row_shr:1
        v2f q2 = fma2(mp2[2], o2, mq2[2]);
        v2f q3 = fma2(mp2[3], o2, mq2[3]);
        l = dpp_add<0x112>(l);                       // row_shr:2
        float e0 = __builtin_amdgcn_exp2f(q0[0]);
        float e1 = __builtin_amdgcn_exp2f(q0[1]);
        l = dpp_add<0x114>(l);                       // row_shr:4
        float e2s = __builtin_amdgcn_exp2f(q1[0]);
        float e3 = __builtin_amdgcn_exp2f(q1[1]);
        l = dpp_add<0x118>(l);                       // row_shr:8
        float e4 = __builtin_amdgcn_exp2f(q2[0]);
        float e5 = __builtin_amdgcn_exp2f(q2[1]);
        l = dpp_add<0x142>(l);                       // row_bcast:15
        float e6 = __builtin_amdgcn_exp2f(q3[0]);
        float e7 = __builtin_amdgcn_exp2f(q3[1]);
        l = dpp_add<0x143>(l);                       // row_bcast:31
        Z = __builtin_bit_cast(float, __builtin_amdgcn_readlane(__builtin_bit_cast(int, l), 63));
        if (renorm) {
            acc2 += __builtin_amdgcn_logf(Z);          // log2(Z)
            const float r = __builtin_amdgcn_rcpf(Z);
            const float cc = 0.9f * r;
            c9v = (v2f){cc, cc};
            kzv = (v2f){KE, KE};
        } else {
            const float kz = KE * Z;
            c9v = (v2f){0.9f, 0.9f};
            kzv = (v2f){kz, kz};
        }
        e2[0] = (v2f){e0, e1}; e2[1] = (v2f){e2s, e3};
        e2[2] = (v2f){e4, e5}; e2[3] = (v2f){e6, e7};
    };

    float oc[8], nx[8];
#pragma unroll
    for (int j = 0; j < 8; ++j) oc[j] = s_obs[j];
#pragma unroll
    for (int j = 0; j < 8; ++j) nx[j] = s_obs[8 + j];

    {   // group 0: init at local step 0 (pi if t0==0, uniform otherwise)
        const v2f o0 = (v2f){oc[0], oc[0]};
#pragma unroll
        for (int i = 0; i < 4; ++i) {
            v2f q = fma2(mp2[i], o0, mq2[i]) + lp2[i];
            a2[i] = (v2f){__builtin_amdgcn_exp2f(q[0]), __builtin_amdgcn_exp2f(q[1])};
        }
        v2f ss = (a2[0] + a2[1]) + (a2[2] + a2[3]);
        float l = ss[0] + ss[1];
        l = dpp_add<0x111>(l); l = dpp_add<0x112>(l); l = dpp_add<0x114>(l);
        l = dpp_add<0x118>(l); l = dpp_add<0x142>(l); l = dpp_add<0x143>(l);
        Z = __builtin_bit_cast(float, __builtin_amdgcn_readlane(__builtin_bit_cast(int, l), 63));
        const float kz = KE * Z;
        c9v = (v2f){0.9f, 0.9f};
        kzv = (v2f){kz, kz};
        const v2f o1 = (v2f){oc[1], oc[1]};      // emissions for local step 1
#pragma unroll
        for (int i = 0; i < 4; ++i) {
            v2f q = fma2(mp2[i], o1, mq2[i]);
            e2[i] = (v2f){__builtin_amdgcn_exp2f(q[0]), __builtin_amdgcn_exp2f(q[1])};
        }
    }
#pragma unroll
    for (int j = 0; j < 8; j += 2)       // osq over group 0 (kept only if c==0)
        osq2 = fma2((v2f){oc[j], oc[j + 1]}, (v2f){oc[j], oc[j + 1]}, osq2);

    // group 0 steps 1..7 (renorm at local 7)
#pragma unroll
    for (int j = 1; j < 7; ++j) stepf(oc[j + 1], false);
    stepf(nx[0], true);
#pragma unroll
    for (int j = 0; j < 8; ++j) oc[j] = nx[j];

    // groups g = 1..ng-1; accumulators reset entering group g_reset (work start)
#pragma unroll 1
    for (int g = 1; g < ng; ++g) {
        const float4 n0 = *reinterpret_cast<const float4*>(&s_obs[8 * g + 8]);
        const float4 n1 = *reinterpret_cast<const float4*>(&s_obs[8 * g + 12]);
        if (g == g_reset) {               // discard burn-in lnZ and osq
            acc2 = 0.0f;
            osq2 = (v2f){0.0f, 0.0f};
        }
#pragma unroll
        for (int j = 0; j < 8; j += 2)
            osq2 = fma2((v2f){oc[j], oc[j + 1]}, (v2f){oc[j], oc[j + 1]}, osq2);
#pragma unroll
        for (int j = 0; j < 7; ++j) stepf(oc[j + 1], false);
        stepf(n0.x, true);
        oc[0] = n0.x; oc[1] = n0.y; oc[2] = n0.z; oc[3] = n0.w;
        oc[4] = n1.x; oc[5] = n1.y; oc[6] = n1.z; oc[7] = n1.w;
    }

    if (lane == 0)
        atomicAdd(out, LN2 * (acc2 + C1 * (osq2[0] + osq2[1])));
}

extern "C" void kernel_launch(void* const* d_in, const int* in_sizes, int n_in,
                              void* d_out, int out_size, void* d_ws, size_t ws_size,
                              hipStream_t stream)
{
    const float* obvs  = (const float*)d_in[0];
    const float* mu    = (const float*)d_in[1];
    const float* ln_pi = (const float*)d_in[2];
    float* out = (float*)d_out;

    (void)hipMemsetAsync(out, 0, sizeof(float), stream);
    hmm_fwd_kernel<<<B_LEN * NCHUNK, 64, 0, stream>>>(obvs, mu, ln_pi, out);
}